// Round 1
// baseline (155.400 us; speedup 1.0000x reference)
//
#include <hip/hip_runtime.h>
#include <cstdint>

// ---------------------------------------------------------------------------
// QuantumBranch: 4-qubit circuit (fixed entangling unitary) + softmax + proj
// + layernorm, fully algebraically collapsed.
//
//   out[b,k] = inv_b * (A[k]·q_b + B0[k]) + beta[k]
//   q_b = softmax(z_b), z_b from two real 16x16 matvecs with the folded
//   circuit matrix V = U * diag((-i)^popc(j)).
//
// Setup kernel (1 block) computes V^T re/im, A=(W-colmean)*gamma, B0, and the
// 4x4 quadratic form (G,g,c0) for the variance, into d_ws.
// Main kernel: 1 sample/thread; all constants read via address_space(4)
// pointers -> s_load (wave-uniform scalars), FMA second operand from SGPRs.
// ---------------------------------------------------------------------------

#define CONST_AS __attribute__((address_space(4)))
template <typename T>
__device__ inline const CONST_AS T* as_const4(const T* p) {
    return (const CONST_AS T*)(uintptr_t)p;
}

// ws float offsets
#define WS_VRT 0     // 256: Re(V)^T  [j*16+i]
#define WS_VIT 256   // 256: Im(V)^T
#define WS_A   512   // 256: (W-colmean)*gamma  [k*4+w]
#define WS_B0  768   // 64:  (b-bmean)*gamma
#define WS_G   832   // 16:  G[4][4]
#define WS_g   848   // 4
#define WS_C0  852   // 1

__global__ void qb_setup(const float* __restrict__ wts, const float* __restrict__ W,
                         const float* __restrict__ bias, const float* __restrict__ gamma,
                         float* __restrict__ ws) {
    __shared__ float2 U[16][16];   // U[row][col], circuit unitary (wire0 = MSB)
    const int tid = threadIdx.x;
    const int row = tid >> 4;
    const int col = tid & 15;
    U[row][col] = make_float2(row == col ? 1.f : 0.f, 0.f);
    __syncthreads();

    #pragma unroll
    for (int l = 0; l < 2; ++l) {
        // Rot gates on wires 0..3
        #pragma unroll
        for (int w = 0; w < 4; ++w) {
            const float ph = wts[l*12 + w*3 + 0];
            const float th = wts[l*12 + w*3 + 1];
            const float om = wts[l*12 + w*3 + 2];
            float st, ct; __sincosf(0.5f*th, &st, &ct);
            float sp, cp; __sincosf(0.5f*(ph+om), &sp, &cp);
            float sm, cm; __sincosf(0.5f*(ph-om), &sm, &cm);
            // ep=(cp,-sp), em=(cm,sm)
            const float2 U00 = make_float2( cp*ct, -sp*ct);   // ep*c
            const float2 U01 = make_float2(-cm*st, -sm*st);   // -em*s
            const float2 U10 = make_float2( cm*st, -sm*st);   // conj(em)*s
            const float2 U11 = make_float2( cp*ct,  sp*ct);   // conj(ep)*c
            const int m = 8 >> w;
            const float2 a = U[row][col];
            const float2 p = U[row ^ m][col];
            float2 nv;
            if ((row & m) == 0) {
                nv = make_float2(U00.x*a.x - U00.y*a.y + U01.x*p.x - U01.y*p.y,
                                 U00.x*a.y + U00.y*a.x + U01.x*p.y + U01.y*p.x);
            } else {
                nv = make_float2(U11.x*a.x - U11.y*a.y + U10.x*p.x - U10.y*p.y,
                                 U11.x*a.y + U11.y*a.x + U10.x*p.y + U10.y*p.x);
            }
            __syncthreads();
            U[row][col] = nv;
            __syncthreads();
        }
        // CNOT ring, range r = l%3+1
        const int rr = (l == 0) ? 1 : 2;
        #pragma unroll
        for (int w = 0; w < 4; ++w) {
            const int cmk = 8 >> w;
            const int tmk = 8 >> ((w + rr) & 3);
            const int src = (row & cmk) ? (row ^ tmk) : row;
            const float2 v = U[src][col];
            __syncthreads();
            U[row][col] = v;
            __syncthreads();
        }
    }

    // V = U * diag((-i)^popc(col));  store transposed (column-major by j)
    {
        const float2 u = U[row][col];
        const int p = __popc(col) & 3;
        float vr, vi;
        if (p == 0)      { vr =  u.x; vi =  u.y; }
        else if (p == 1) { vr =  u.y; vi = -u.x; }
        else if (p == 2) { vr = -u.x; vi = -u.y; }
        else             { vr = -u.y; vi =  u.x; }
        ws[WS_VRT + col*16 + row] = vr;
        ws[WS_VIT + col*16 + row] = vi;
    }

    // Projection/layernorm constants (wave 0, lane k)
    if (tid < 64) {
        const int k = tid;
        float w0 = W[k*4+0], w1 = W[k*4+1], w2 = W[k*4+2], w3 = W[k*4+3];
        float bk = bias[k];
        auto wsum = [](float v) {
            #pragma unroll
            for (int o = 32; o; o >>= 1) v += __shfl_xor(v, o, 64);
            return v;
        };
        const float inv64 = 1.f/64.f;
        const float m0 = wsum(w0)*inv64, m1 = wsum(w1)*inv64;
        const float m2 = wsum(w2)*inv64, m3 = wsum(w3)*inv64;
        const float bm = wsum(bk)*inv64;
        float cc[4] = {w0-m0, w1-m1, w2-m2, w3-m3};
        const float bc = bk - bm;
        const float gk = gamma[k];
        #pragma unroll
        for (int w = 0; w < 4; ++w) ws[WS_A + k*4 + w] = cc[w]*gk;
        ws[WS_B0 + k] = bc*gk;
        #pragma unroll
        for (int a = 0; a < 4; ++a)
            #pragma unroll
            for (int b2 = 0; b2 < 4; ++b2) {
                const float s = wsum(cc[a]*cc[b2])*inv64;
                if (k == 0) ws[WS_G + a*4 + b2] = s;
            }
        #pragma unroll
        for (int a = 0; a < 4; ++a) {
            const float s = wsum(bc*cc[a])*inv64;
            if (k == 0) ws[WS_g + a] = s;
        }
        {
            const float s = wsum(bc*bc)*inv64;
            if (k == 0) ws[WS_C0] = s;
        }
    }
}

__global__ __launch_bounds__(256) void qb_main(const float* __restrict__ x,
                                               const float* __restrict__ beta,
                                               const float* __restrict__ ws_g,
                                               float* __restrict__ out) {
    const int sample = blockIdx.x * 256 + threadIdx.x;
    const float4 xv = ((const float4*)x)[sample];
    const float xa[4] = {xv.x, xv.y, xv.z, xv.w};

    // embedding: angles = tanh(x)*pi, half-angle cos/sin
    float c[4], s[4];
    #pragma unroll
    for (int w = 0; w < 4; ++w) {
        const float h = tanhf(xa[w]) * 1.5707963267948966f;
        __sincosf(h, &s[w], &c[w]);
    }
    // product-state magnitudes m[j], wire0 = MSB
    const float e01[4] = {c[0]*c[1], c[0]*s[1], s[0]*c[1], s[0]*s[1]};
    const float e23[4] = {c[2]*c[3], c[2]*s[3], s[2]*c[3], s[2]*s[3]};
    float m[16];
    #pragma unroll
    for (int j = 0; j < 16; ++j) m[j] = e01[j>>2]*e23[j&3];

    const CONST_AS float* V = as_const4(ws_g);
    float r[16], si[16];
    #pragma unroll
    for (int i = 0; i < 16; ++i) { r[i] = 0.f; si[i] = 0.f; }
    #pragma unroll
    for (int j = 0; j < 16; ++j) {
        const float mj = m[j];
        #pragma unroll
        for (int i = 0; i < 16; ++i) {
            r[i]  = fmaf(V[WS_VRT + j*16 + i], mj, r[i]);
            si[i] = fmaf(V[WS_VIT + j*16 + i], mj, si[i]);
        }
    }
    // PauliZ expvals
    float z0 = 0.f, z1 = 0.f, z2 = 0.f, z3 = 0.f;
    #pragma unroll
    for (int i = 0; i < 16; ++i) {
        const float p = r[i]*r[i] + si[i]*si[i];
        z0 += (i & 8) ? -p : p;
        z1 += (i & 4) ? -p : p;
        z2 += (i & 2) ? -p : p;
        z3 += (i & 1) ? -p : p;
    }
    // softmax over 4
    const float mx = fmaxf(fmaxf(z0, z1), fmaxf(z2, z3));
    const float e0 = __expf(z0-mx), e1 = __expf(z1-mx);
    const float e2 = __expf(z2-mx), e3 = __expf(z3-mx);
    const float rs = 1.f / (e0+e1+e2+e3);
    const float qv[4] = {e0*rs, e1*rs, e2*rs, e3*rs};

    // var = q^T G q + 2 g.q + c0 ; inv = rsqrt(var+eps)
    float var = V[WS_C0];
    #pragma unroll
    for (int a = 0; a < 4; ++a) {
        float t = 2.f * V[WS_g + a];
        #pragma unroll
        for (int b2 = 0; b2 < 4; ++b2) t = fmaf(V[WS_G + a*4 + b2], qv[b2], t);
        var = fmaf(qv[a], t, var);
    }
    const float inv = rsqrtf(var + 1e-5f);

    const CONST_AS float* betac = as_const4(beta);
    float4* outv = (float4*)(out + (size_t)sample * 64);
    #pragma unroll
    for (int k4 = 0; k4 < 16; ++k4) {
        float4 o;
        float* op = (float*)&o;
        #pragma unroll
        for (int u = 0; u < 4; ++u) {
            const int k = k4*4 + u;
            float t = V[WS_B0 + k];
            #pragma unroll
            for (int w = 0; w < 4; ++w) t = fmaf(V[WS_A + k*4 + w], qv[w], t);
            op[u] = fmaf(t, inv, betac[k]);
        }
        outv[k4] = o;
    }
}

extern "C" void kernel_launch(void* const* d_in, const int* in_sizes, int n_in,
                              void* d_out, int out_size, void* d_ws, size_t ws_size,
                              hipStream_t stream) {
    const float* x     = (const float*)d_in[0];
    const float* wts   = (const float*)d_in[1];
    const float* W     = (const float*)d_in[2];
    const float* bias  = (const float*)d_in[3];
    const float* gamma = (const float*)d_in[4];
    const float* beta  = (const float*)d_in[5];
    float* out = (float*)d_out;
    float* ws  = (float*)d_ws;
    const int B = in_sizes[0] / 4;   // 262144

    hipLaunchKernelGGL(qb_setup, dim3(1), dim3(256), 0, stream, wts, W, bias, gamma, ws);
    hipLaunchKernelGGL(qb_main, dim3(B / 256), dim3(256), 0, stream, x, beta, ws, out);
}

// Round 2
// 98.149 us; speedup vs baseline: 1.5833x; 1.5833x over previous
//
#include <hip/hip_runtime.h>
#include <cstdint>

// ---------------------------------------------------------------------------
// QuantumBranch, R2: same algebraic collapse as R1, but the output write
// phase is restructured for full wave coalescing.
//
// R1 failure mode (measured): one thread wrote one sample's 256B block with
// 16x float4 stores -> per store instruction, 64 lanes hit 64 different
// cache lines (stride 256B) -> WRITE_SIZE 321 MB vs 67 MB ideal (4.8x).
//
// R2: phase 1 computes q[4] + inv per sample into LDS (5 floats/sample);
// phase 2 writes the block's 256x64 output tile with flat index
// f = iter*256 + tid (float4 units) -> each wave store covers contiguous
// 1 KiB. k4 = tid&15 is iter-invariant so A/B0/beta coefficients are
// preloaded into registers once per thread.
// ---------------------------------------------------------------------------

#define CONST_AS __attribute__((address_space(4)))
template <typename T>
__device__ inline const CONST_AS T* as_const4(const T* p) {
    return (const CONST_AS T*)(uintptr_t)p;
}

typedef float v4f __attribute__((ext_vector_type(4)));

// ws float offsets
#define WS_VRT 0     // 256: Re(V)^T  [j*16+i]
#define WS_VIT 256   // 256: Im(V)^T
#define WS_A   512   // 256: (W-colmean)*gamma  [k*4+w]
#define WS_B0  768   // 64:  (b-bmean)*gamma
#define WS_G   832   // 16:  G[4][4]
#define WS_g   848   // 4
#define WS_C0  852   // 1

__global__ void qb_setup(const float* __restrict__ wts, const float* __restrict__ W,
                         const float* __restrict__ bias, const float* __restrict__ gamma,
                         float* __restrict__ ws) {
    __shared__ float2 U[16][16];   // U[row][col], circuit unitary (wire0 = MSB)
    const int tid = threadIdx.x;
    const int row = tid >> 4;
    const int col = tid & 15;
    U[row][col] = make_float2(row == col ? 1.f : 0.f, 0.f);
    __syncthreads();

    #pragma unroll
    for (int l = 0; l < 2; ++l) {
        #pragma unroll
        for (int w = 0; w < 4; ++w) {
            const float ph = wts[l*12 + w*3 + 0];
            const float th = wts[l*12 + w*3 + 1];
            const float om = wts[l*12 + w*3 + 2];
            float st, ct; __sincosf(0.5f*th, &st, &ct);
            float sp, cp; __sincosf(0.5f*(ph+om), &sp, &cp);
            float sm, cm; __sincosf(0.5f*(ph-om), &sm, &cm);
            const float2 U00 = make_float2( cp*ct, -sp*ct);
            const float2 U01 = make_float2(-cm*st, -sm*st);
            const float2 U10 = make_float2( cm*st, -sm*st);
            const float2 U11 = make_float2( cp*ct,  sp*ct);
            const int m = 8 >> w;
            const float2 a = U[row][col];
            const float2 p = U[row ^ m][col];
            float2 nv;
            if ((row & m) == 0) {
                nv = make_float2(U00.x*a.x - U00.y*a.y + U01.x*p.x - U01.y*p.y,
                                 U00.x*a.y + U00.y*a.x + U01.x*p.y + U01.y*p.x);
            } else {
                nv = make_float2(U11.x*a.x - U11.y*a.y + U10.x*p.x - U10.y*p.y,
                                 U11.x*a.y + U11.y*a.x + U10.x*p.y + U10.y*p.x);
            }
            __syncthreads();
            U[row][col] = nv;
            __syncthreads();
        }
        const int rr = (l == 0) ? 1 : 2;
        #pragma unroll
        for (int w = 0; w < 4; ++w) {
            const int cmk = 8 >> w;
            const int tmk = 8 >> ((w + rr) & 3);
            const int src = (row & cmk) ? (row ^ tmk) : row;
            const float2 v = U[src][col];
            __syncthreads();
            U[row][col] = v;
            __syncthreads();
        }
    }

    {
        const float2 u = U[row][col];
        const int p = __popc(col) & 3;
        float vr, vi;
        if (p == 0)      { vr =  u.x; vi =  u.y; }
        else if (p == 1) { vr =  u.y; vi = -u.x; }
        else if (p == 2) { vr = -u.x; vi = -u.y; }
        else             { vr = -u.y; vi =  u.x; }
        ws[WS_VRT + col*16 + row] = vr;
        ws[WS_VIT + col*16 + row] = vi;
    }

    if (tid < 64) {
        const int k = tid;
        float w0 = W[k*4+0], w1 = W[k*4+1], w2 = W[k*4+2], w3 = W[k*4+3];
        float bk = bias[k];
        auto wsum = [](float v) {
            #pragma unroll
            for (int o = 32; o; o >>= 1) v += __shfl_xor(v, o, 64);
            return v;
        };
        const float inv64 = 1.f/64.f;
        const float m0 = wsum(w0)*inv64, m1 = wsum(w1)*inv64;
        const float m2 = wsum(w2)*inv64, m3 = wsum(w3)*inv64;
        const float bm = wsum(bk)*inv64;
        float cc[4] = {w0-m0, w1-m1, w2-m2, w3-m3};
        const float bc = bk - bm;
        const float gk = gamma[k];
        #pragma unroll
        for (int w = 0; w < 4; ++w) ws[WS_A + k*4 + w] = cc[w]*gk;
        ws[WS_B0 + k] = bc*gk;
        #pragma unroll
        for (int a = 0; a < 4; ++a)
            #pragma unroll
            for (int b2 = 0; b2 < 4; ++b2) {
                const float s = wsum(cc[a]*cc[b2])*inv64;
                if (k == 0) ws[WS_G + a*4 + b2] = s;
            }
        #pragma unroll
        for (int a = 0; a < 4; ++a) {
            const float s = wsum(bc*cc[a])*inv64;
            if (k == 0) ws[WS_g + a] = s;
        }
        {
            const float s = wsum(bc*bc)*inv64;
            if (k == 0) ws[WS_C0] = s;
        }
    }
}

__global__ __launch_bounds__(256) void qb_main(const float* __restrict__ x,
                                               const float* __restrict__ beta,
                                               const float* __restrict__ ws_g,
                                               float* __restrict__ out) {
    __shared__ float4 lq[256];
    __shared__ float  linv[256];

    const int tid = threadIdx.x;
    const int sample = blockIdx.x * 256 + tid;
    const float4 xv = ((const float4*)x)[sample];
    const float xa[4] = {xv.x, xv.y, xv.z, xv.w};

    // --- phase 2 coefficient preload (independent of phase 1; issues early) ---
    const int k4t = tid & 15;            // this thread's float4 column, iter-invariant
    float4 A4[4]; float B04[4], Bt4[4];
    #pragma unroll
    for (int u = 0; u < 4; ++u) {
        const int k = k4t*4 + u;
        A4[u]  = ((const float4*)(ws_g + WS_A))[k];
        B04[u] = ws_g[WS_B0 + k];
        Bt4[u] = beta[k];
    }

    // --- phase 1: per-sample circuit -> q, inv ---
    float c[4], s[4];
    #pragma unroll
    for (int w = 0; w < 4; ++w) {
        const float h = tanhf(xa[w]) * 1.5707963267948966f;
        __sincosf(h, &s[w], &c[w]);
    }
    const float e01[4] = {c[0]*c[1], c[0]*s[1], s[0]*c[1], s[0]*s[1]};
    const float e23[4] = {c[2]*c[3], c[2]*s[3], s[2]*c[3], s[2]*s[3]};
    float m[16];
    #pragma unroll
    for (int j = 0; j < 16; ++j) m[j] = e01[j>>2]*e23[j&3];

    const CONST_AS float* V = as_const4(ws_g);
    float r[16], si[16];
    #pragma unroll
    for (int i = 0; i < 16; ++i) { r[i] = 0.f; si[i] = 0.f; }
    #pragma unroll
    for (int j = 0; j < 16; ++j) {
        const float mj = m[j];
        #pragma unroll
        for (int i = 0; i < 16; ++i) {
            r[i]  = fmaf(V[WS_VRT + j*16 + i], mj, r[i]);
            si[i] = fmaf(V[WS_VIT + j*16 + i], mj, si[i]);
        }
    }
    float z0 = 0.f, z1 = 0.f, z2 = 0.f, z3 = 0.f;
    #pragma unroll
    for (int i = 0; i < 16; ++i) {
        const float p = r[i]*r[i] + si[i]*si[i];
        z0 += (i & 8) ? -p : p;
        z1 += (i & 4) ? -p : p;
        z2 += (i & 2) ? -p : p;
        z3 += (i & 1) ? -p : p;
    }
    const float mx = fmaxf(fmaxf(z0, z1), fmaxf(z2, z3));
    const float e0 = __expf(z0-mx), e1 = __expf(z1-mx);
    const float e2 = __expf(z2-mx), e3 = __expf(z3-mx);
    const float rs = 1.f / (e0+e1+e2+e3);
    const float4 qv = make_float4(e0*rs, e1*rs, e2*rs, e3*rs);

    float var = V[WS_C0];
    {
        const float qa[4] = {qv.x, qv.y, qv.z, qv.w};
        #pragma unroll
        for (int a = 0; a < 4; ++a) {
            float t = 2.f * V[WS_g + a];
            #pragma unroll
            for (int b2 = 0; b2 < 4; ++b2) t = fmaf(V[WS_G + a*4 + b2], qa[b2], t);
            var = fmaf(qa[a], t, var);
        }
    }
    const float inv = rsqrtf(var + 1e-5f);

    lq[tid]   = qv;
    linv[tid] = inv;
    __syncthreads();

    // --- phase 2: coalesced tile write. Block tile = 256 samples x 16 float4s.
    // flat f = iter*256 + tid -> consecutive lanes write consecutive float4s.
    v4f* outv = (v4f*)((float4*)out + (size_t)blockIdx.x * 4096);
    #pragma unroll
    for (int iter = 0; iter < 16; ++iter) {
        const int f  = iter*256 + tid;
        const int sl = f >> 4;               // local sample; 16 lanes share one
        const float4 q  = lq[sl];
        const float  iv = linv[sl];
        v4f o;
        #pragma unroll
        for (int u = 0; u < 4; ++u) {
            float t = B04[u];
            t = fmaf(A4[u].x, q.x, t);
            t = fmaf(A4[u].y, q.y, t);
            t = fmaf(A4[u].z, q.z, t);
            t = fmaf(A4[u].w, q.w, t);
            o[u] = fmaf(t, iv, Bt4[u]);
        }
        __builtin_nontemporal_store(o, outv + f);
    }
}

extern "C" void kernel_launch(void* const* d_in, const int* in_sizes, int n_in,
                              void* d_out, int out_size, void* d_ws, size_t ws_size,
                              hipStream_t stream) {
    const float* x     = (const float*)d_in[0];
    const float* wts   = (const float*)d_in[1];
    const float* W     = (const float*)d_in[2];
    const float* bias  = (const float*)d_in[3];
    const float* gamma = (const float*)d_in[4];
    const float* beta  = (const float*)d_in[5];
    float* out = (float*)d_out;
    float* ws  = (float*)d_ws;
    const int B = in_sizes[0] / 4;   // 262144

    hipLaunchKernelGGL(qb_setup, dim3(1), dim3(256), 0, stream, wts, W, bias, gamma, ws);
    hipLaunchKernelGGL(qb_main, dim3(B / 256), dim3(256), 0, stream, x, beta, ws, out);
}

// Round 3
// 97.215 us; speedup vs baseline: 1.5985x; 1.0096x over previous
//
#include <hip/hip_runtime.h>
#include <cstdint>

// ---------------------------------------------------------------------------
// QuantumBranch, R3.
// R2 post-mortem: coalesced write phase took qb_main 82.8 -> ~26us (est).
// Remaining levers: (1) nontemporal stores bypass L2 write-combining ->
// switch to plain stores so L2 assembles full lines; (2) setup kernel had
// 32 __syncthreads in a 4-wave block -> rewritten as ONE wave, zero
// barriers, unitary held in registers (4 complex entries/lane), cross-row
// gate pairing via shfl_xor, CNOT row-permutation via variable shfl.
//
// Math (unchanged, verified R1/R2): circuit collapses to V = U*diag((-i)^popc),
// z_w = sum_i +/- (r_i^2+s_i^2) with r=Re(V)m, s=Im(V)m, m = product-state
// magnitudes from tanh(x)*pi/2. LayerNorm collapses to a 4x4 quadratic form.
// out[b,k] = inv_b*(A[k].q_b + B0[k]) + beta[k].
// ---------------------------------------------------------------------------

#define CONST_AS __attribute__((address_space(4)))
template <typename T>
__device__ inline const CONST_AS T* as_const4(const T* p) {
    return (const CONST_AS T*)(uintptr_t)p;
}

typedef float v4f __attribute__((ext_vector_type(4)));

// ws float offsets
#define WS_VRT 0     // 256: Re(V)^T  [j*16+i]
#define WS_VIT 256   // 256: Im(V)^T
#define WS_A   512   // 256: (W-colmean)*gamma  [k*4+w]
#define WS_B0  768   // 64:  (b-bmean)*gamma
#define WS_G   832   // 16:  G[4][4]
#define WS_g   848   // 4
#define WS_C0  852   // 1

// One wave, no barriers. lane = row*4 + cg; lane holds U[row][4cg..4cg+3].
__global__ __launch_bounds__(64) void qb_setup(const float* __restrict__ wts,
                                               const float* __restrict__ W,
                                               const float* __restrict__ bias,
                                               const float* __restrict__ gamma,
                                               float* __restrict__ ws) {
    const int lane = threadIdx.x;
    const int row  = lane >> 2;
    const int cg   = lane & 3;

    float ur[4], ui[4];   // U[row][4cg+c]
    #pragma unroll
    for (int c = 0; c < 4; ++c) {
        ur[c] = (row == 4*cg + c) ? 1.f : 0.f;
        ui[c] = 0.f;
    }

    #pragma unroll
    for (int l = 0; l < 2; ++l) {
        // Rot on wires 0..3 (wire0 = MSB of row index)
        #pragma unroll
        for (int w = 0; w < 4; ++w) {
            const float ph = wts[l*12 + w*3 + 0];
            const float th = wts[l*12 + w*3 + 1];
            const float om = wts[l*12 + w*3 + 2];
            float st, ct; __sincosf(0.5f*th, &st, &ct);
            float sp, cp; __sincosf(0.5f*(ph+om), &sp, &cp);
            float sm, cm; __sincosf(0.5f*(ph-om), &sm, &cm);
            // U00=ep*c=(cp*ct,-sp*ct)  U01=-em*s=(-cm*st,-sm*st)
            // U10=conj(em)*s=(cm*st,-sm*st)  U11=conj(ep)*c=(cp*ct,sp*ct)
            const float a00r =  cp*ct, a00i = -sp*ct;
            const float a01r = -cm*st, a01i = -sm*st;
            const float a10r =  cm*st, a10i = -sm*st;
            const float a11r =  cp*ct, a11i =  sp*ct;
            const int m = 8 >> w;
            const int xm = m << 2;            // lane xor mask for row^m
            const bool hi = (row & m) != 0;
            #pragma unroll
            for (int c = 0; c < 4; ++c) {
                const float pr = __shfl_xor(ur[c], xm, 64);
                const float pi = __shfl_xor(ui[c], xm, 64);
                float nr, ni;
                if (!hi) {
                    nr = a00r*ur[c] - a00i*ui[c] + a01r*pr - a01i*pi;
                    ni = a00r*ui[c] + a00i*ur[c] + a01r*pi + a01i*pr;
                } else {
                    nr = a11r*ur[c] - a11i*ui[c] + a10r*pr - a10i*pi;
                    ni = a11r*ui[c] + a11i*ur[c] + a10r*pi + a10i*pr;
                }
                ur[c] = nr; ui[c] = ni;
            }
        }
        // CNOT ring, range r = l%3+1: new[row] = old[src(row)]
        const int rr = (l == 0) ? 1 : 2;
        #pragma unroll
        for (int w = 0; w < 4; ++w) {
            const int cmk = 8 >> w;
            const int tmk = 8 >> ((w + rr) & 3);
            const int src = (row & cmk) ? (row ^ tmk) : row;
            const int srcLane = src*4 + cg;
            #pragma unroll
            for (int c = 0; c < 4; ++c) {
                ur[c] = __shfl(ur[c], srcLane, 64);
                ui[c] = __shfl(ui[c], srcLane, 64);
            }
        }
    }

    // V = U * diag((-i)^popc(col)); store transposed: ws[VRT + col*16 + row]
    #pragma unroll
    for (int c = 0; c < 4; ++c) {
        const int col = 4*cg + c;
        const int p = __popc(col) & 3;
        float vr, vi;
        if (p == 0)      { vr =  ur[c]; vi =  ui[c]; }
        else if (p == 1) { vr =  ui[c]; vi = -ur[c]; }
        else if (p == 2) { vr = -ur[c]; vi = -ui[c]; }
        else             { vr = -ui[c]; vi =  ur[c]; }
        ws[WS_VRT + col*16 + row] = vr;
        ws[WS_VIT + col*16 + row] = vi;
    }

    // Projection / layernorm constants: lane k
    {
        const int k = lane;
        float w0 = W[k*4+0], w1 = W[k*4+1], w2 = W[k*4+2], w3 = W[k*4+3];
        float bk = bias[k];
        auto wsum = [](float v) {
            #pragma unroll
            for (int o = 32; o; o >>= 1) v += __shfl_xor(v, o, 64);
            return v;
        };
        const float inv64 = 1.f/64.f;
        const float m0 = wsum(w0)*inv64, m1 = wsum(w1)*inv64;
        const float m2 = wsum(w2)*inv64, m3 = wsum(w3)*inv64;
        const float bm = wsum(bk)*inv64;
        float cc[4] = {w0-m0, w1-m1, w2-m2, w3-m3};
        const float bc = bk - bm;
        const float gk = gamma[k];
        #pragma unroll
        for (int w = 0; w < 4; ++w) ws[WS_A + k*4 + w] = cc[w]*gk;
        ws[WS_B0 + k] = bc*gk;
        #pragma unroll
        for (int a = 0; a < 4; ++a)
            #pragma unroll
            for (int b2 = 0; b2 < 4; ++b2) {
                const float s = wsum(cc[a]*cc[b2])*inv64;
                if (k == 0) ws[WS_G + a*4 + b2] = s;
            }
        #pragma unroll
        for (int a = 0; a < 4; ++a) {
            const float s = wsum(bc*cc[a])*inv64;
            if (k == 0) ws[WS_g + a] = s;
        }
        {
            const float s = wsum(bc*bc)*inv64;
            if (k == 0) ws[WS_C0] = s;
        }
    }
}

__global__ __launch_bounds__(256) void qb_main(const float* __restrict__ x,
                                               const float* __restrict__ beta,
                                               const float* __restrict__ ws_g,
                                               float* __restrict__ out) {
    __shared__ float4 lq[256];
    __shared__ float  linv[256];

    const int tid = threadIdx.x;
    const int sample = blockIdx.x * 256 + tid;
    const float4 xv = ((const float4*)x)[sample];
    const float xa[4] = {xv.x, xv.y, xv.z, xv.w};

    // phase 2 coefficient preload (iter-invariant column tid&15)
    const int k4t = tid & 15;
    float4 A4[4]; float B04[4], Bt4[4];
    #pragma unroll
    for (int u = 0; u < 4; ++u) {
        const int k = k4t*4 + u;
        A4[u]  = ((const float4*)(ws_g + WS_A))[k];
        B04[u] = ws_g[WS_B0 + k];
        Bt4[u] = beta[k];
    }

    // phase 1: per-sample circuit -> q, inv
    float c[4], s[4];
    #pragma unroll
    for (int w = 0; w < 4; ++w) {
        const float h = tanhf(xa[w]) * 1.5707963267948966f;
        __sincosf(h, &s[w], &c[w]);
    }
    const float e01[4] = {c[0]*c[1], c[0]*s[1], s[0]*c[1], s[0]*s[1]};
    const float e23[4] = {c[2]*c[3], c[2]*s[3], s[2]*c[3], s[2]*s[3]};
    float m[16];
    #pragma unroll
    for (int j = 0; j < 16; ++j) m[j] = e01[j>>2]*e23[j&3];

    const CONST_AS float* V = as_const4(ws_g);
    float r[16], si[16];
    #pragma unroll
    for (int i = 0; i < 16; ++i) { r[i] = 0.f; si[i] = 0.f; }
    #pragma unroll
    for (int j = 0; j < 16; ++j) {
        const float mj = m[j];
        #pragma unroll
        for (int i = 0; i < 16; ++i) {
            r[i]  = fmaf(V[WS_VRT + j*16 + i], mj, r[i]);
            si[i] = fmaf(V[WS_VIT + j*16 + i], mj, si[i]);
        }
    }
    float z0 = 0.f, z1 = 0.f, z2 = 0.f, z3 = 0.f;
    #pragma unroll
    for (int i = 0; i < 16; ++i) {
        const float p = r[i]*r[i] + si[i]*si[i];
        z0 += (i & 8) ? -p : p;
        z1 += (i & 4) ? -p : p;
        z2 += (i & 2) ? -p : p;
        z3 += (i & 1) ? -p : p;
    }
    const float mx = fmaxf(fmaxf(z0, z1), fmaxf(z2, z3));
    const float e0 = __expf(z0-mx), e1 = __expf(z1-mx);
    const float e2 = __expf(z2-mx), e3 = __expf(z3-mx);
    const float rs = 1.f / (e0+e1+e2+e3);
    const float4 qv = make_float4(e0*rs, e1*rs, e2*rs, e3*rs);

    float var = V[WS_C0];
    {
        const float qa[4] = {qv.x, qv.y, qv.z, qv.w};
        #pragma unroll
        for (int a = 0; a < 4; ++a) {
            float t = 2.f * V[WS_g + a];
            #pragma unroll
            for (int b2 = 0; b2 < 4; ++b2) t = fmaf(V[WS_G + a*4 + b2], qa[b2], t);
            var = fmaf(qa[a], t, var);
        }
    }
    const float inv = rsqrtf(var + 1e-5f);

    lq[tid]   = qv;
    linv[tid] = inv;
    __syncthreads();

    // phase 2: coalesced tile write; plain stores (L2 write-combining).
    float4* outv = (float4*)out + (size_t)blockIdx.x * 4096;
    #pragma unroll
    for (int iter = 0; iter < 16; ++iter) {
        const int f  = iter*256 + tid;
        const int sl = f >> 4;               // 16 lanes share one sample
        const float4 q  = lq[sl];
        const float  iv = linv[sl];
        float4 o;
        float* op = (float*)&o;
        #pragma unroll
        for (int u = 0; u < 4; ++u) {
            float t = B04[u];
            t = fmaf(A4[u].x, q.x, t);
            t = fmaf(A4[u].y, q.y, t);
            t = fmaf(A4[u].z, q.z, t);
            t = fmaf(A4[u].w, q.w, t);
            op[u] = fmaf(t, iv, Bt4[u]);
        }
        outv[f] = o;
    }
}

extern "C" void kernel_launch(void* const* d_in, const int* in_sizes, int n_in,
                              void* d_out, int out_size, void* d_ws, size_t ws_size,
                              hipStream_t stream) {
    const float* x     = (const float*)d_in[0];
    const float* wts   = (const float*)d_in[1];
    const float* W     = (const float*)d_in[2];
    const float* bias  = (const float*)d_in[3];
    const float* gamma = (const float*)d_in[4];
    const float* beta  = (const float*)d_in[5];
    float* out = (float*)d_out;
    float* ws  = (float*)d_ws;
    const int B = in_sizes[0] / 4;   // 262144

    hipLaunchKernelGGL(qb_setup, dim3(1), dim3(64), 0, stream, wts, W, bias, gamma, ws);
    hipLaunchKernelGGL(qb_main, dim3(B / 256), dim3(256), 0, stream, x, beta, ws, out);
}